// Round 1
// baseline (614.419 us; speedup 1.0000x reference)
//
#include <hip/hip_runtime.h>

#define C_IN 32
#define C_OUT 64
#define BATCH 4
#define HH 128
#define WW 128
#define KK 7
#define PAD 3
#define TILE 16
#define HALO (TILE + KK - 1)  // 22

// Weff layout: [C_IN][49][C_OUT]   (c, p = ky*7+kx, o)  -> 100352 floats
// Beff: 64 floats, stored right after Weff in d_ws.

__global__ __launch_bounds__(256) void prep_weff(
    const float* __restrict__ w3, const float* __restrict__ w5,
    const float* __restrict__ w7, const float* __restrict__ wf,
    float* __restrict__ Weff)
{
    const int c = blockIdx.x;
    __shared__ float lwf[C_OUT * 49];   // wf[o][k-slot] for this input channel c
    __shared__ float lw3[9 * 9];
    __shared__ float lw5[16 * 25];
    __shared__ float lw7[24 * 49];
    const int tid = threadIdx.x;

    for (int idx = tid; idx < C_OUT * 49; idx += 256) {
        int o = idx / 49, k = idx % 49;
        int j = (k < 9)  ? (c * 9 + k)
              : (k < 25) ? (288 + c * 16 + (k - 9))
                         : (800 + c * 24 + (k - 25));
        lwf[idx] = wf[o * 1568 + j];
    }
    for (int idx = tid; idx < 81;   idx += 256) lw3[idx] = w3[c * 81 + idx];
    for (int idx = tid; idx < 400;  idx += 256) lw5[idx] = w5[c * 400 + idx];
    for (int idx = tid; idx < 1176; idx += 256) lw7[idx] = w7[c * 1176 + idx];
    __syncthreads();

    for (int idx = tid; idx < 49 * C_OUT; idx += 256) {
        int o = idx % C_OUT;        // o fastest -> coalesced store
        int p = idx / C_OUT;
        int ky = p / 7, kx = p % 7;
        float acc = 0.f;
        if (ky >= 2 && ky <= 4 && kx >= 2 && kx <= 4) {
            int pos = (ky - 2) * 3 + (kx - 2);
            #pragma unroll
            for (int k = 0; k < 9; ++k)
                acc += lwf[o * 49 + k] * lw3[k * 9 + pos];
        }
        if (ky >= 1 && ky <= 5 && kx >= 1 && kx <= 5) {
            int pos = (ky - 1) * 5 + (kx - 1);
            #pragma unroll
            for (int k = 0; k < 16; ++k)
                acc += lwf[o * 49 + 9 + k] * lw5[k * 25 + pos];
        }
        {
            int pos = ky * 7 + kx;
            #pragma unroll
            for (int k = 0; k < 24; ++k)
                acc += lwf[o * 49 + 25 + k] * lw7[k * 49 + pos];
        }
        Weff[(c * 49 + p) * C_OUT + o] = acc;
    }
}

__global__ __launch_bounds__(256) void prep_beff(
    const float* __restrict__ b3, const float* __restrict__ b5,
    const float* __restrict__ b7, const float* __restrict__ wf,
    const float* __restrict__ bf, float* __restrict__ Beff)
{
    const int o = blockIdx.x;
    const int tid = threadIdx.x;
    float acc = 0.f;
    for (int j = tid; j < 1568; j += 256) {
        float bj = (j < 288) ? b3[j] : (j < 800) ? b5[j - 288] : b7[j - 800];
        acc += wf[o * 1568 + j] * bj;
    }
    __shared__ float red[256];
    red[tid] = acc;
    __syncthreads();
    for (int s = 128; s > 0; s >>= 1) {
        if (tid < s) red[tid] += red[tid + s];
        __syncthreads();
    }
    if (tid == 0) Beff[o] = red[0] + bf[o];
}

__global__ __launch_bounds__(256) void conv7(
    const float* __restrict__ x, const float* __restrict__ Weff,
    const float* __restrict__ Beff, float* __restrict__ out)
{
    __shared__ float xt[C_IN][HALO][HALO];   // 32*22*22*4 = 61952 B
    const int b  = blockIdx.z;
    const int h0 = blockIdx.y * TILE;
    const int w0 = blockIdx.x * TILE;
    const int tid = threadIdx.x;

    const float* xb = x + (size_t)b * C_IN * HH * WW;
    for (int idx = tid; idx < C_IN * HALO * HALO; idx += 256) {
        int c   = idx / (HALO * HALO);
        int rem = idx % (HALO * HALO);
        int r   = rem / HALO, col = rem % HALO;
        int h = h0 + r - PAD, w = w0 + col - PAD;
        float v = 0.f;
        if (h >= 0 && h < HH && w >= 0 && w < WW)
            v = xb[(c * HH + h) * WW + w];
        (&xt[0][0][0])[idx] = v;
    }
    __syncthreads();

    const int tx = tid % 16, ty = tid / 16;
    const int hh = h0 + ty, ww = w0 + tx;

    for (int oc = 0; oc < 4; ++oc) {
        float acc[16];
        #pragma unroll
        for (int o = 0; o < 16; ++o) acc[o] = 0.f;

        for (int c = 0; c < C_IN; ++c) {
            #pragma unroll
            for (int dy = 0; dy < 7; ++dy) {
                float xr[7];
                #pragma unroll
                for (int j = 0; j < 7; ++j) xr[j] = xt[c][ty + dy][tx + j];
                const float* __restrict__ wq =
                    Weff + (c * 49 + dy * 7) * C_OUT + oc * 16;
                #pragma unroll
                for (int dx = 0; dx < 7; ++dx) {
                    #pragma unroll
                    for (int o = 0; o < 16; ++o)
                        acc[o] += xr[dx] * wq[dx * C_OUT + o];
                }
            }
        }

        #pragma unroll
        for (int o = 0; o < 16; ++o) {
            int och = oc * 16 + o;
            out[(((size_t)b * C_OUT + och) * HH + hh) * WW + ww] =
                acc[o] + Beff[och];
        }
    }
}

extern "C" void kernel_launch(void* const* d_in, const int* in_sizes, int n_in,
                              void* d_out, int out_size, void* d_ws, size_t ws_size,
                              hipStream_t stream) {
    const float* x  = (const float*)d_in[0];
    const float* w3 = (const float*)d_in[1];
    const float* b3 = (const float*)d_in[2];
    const float* w5 = (const float*)d_in[3];
    const float* b5 = (const float*)d_in[4];
    const float* w7 = (const float*)d_in[5];
    const float* b7 = (const float*)d_in[6];
    const float* wf = (const float*)d_in[7];
    const float* bf = (const float*)d_in[8];
    float* outp = (float*)d_out;

    float* Weff = (float*)d_ws;
    float* Beff = Weff + C_IN * 49 * C_OUT;

    prep_weff<<<C_IN, 256, 0, stream>>>(w3, w5, w7, wf, Weff);
    prep_beff<<<C_OUT, 256, 0, stream>>>(b3, b5, b7, wf, bf, Beff);

    dim3 grid(WW / TILE, HH / TILE, BATCH);
    conv7<<<grid, 256, 0, stream>>>(x, Weff, Beff, outp);
}

// Round 3
// 264.303 us; speedup vs baseline: 2.3247x; 2.3247x over previous
//
#include <hip/hip_runtime.h>

#define C_IN 32
#define C_OUT 64
#define BATCH 4
#define HH 128
#define WW 128
#define KK 7
#define PAD 3
#define TILE 16
#define HALO (TILE + KK - 1)   // 22
#define RSTRIDE 24             // padded row stride (words) -> conflict-free b128

// Weff layout: [C_IN][49][C_OUT]  (c, p = ky*7+kx, o) -> 100352 floats
// Beff: 64 floats right after Weff in d_ws.

__global__ __launch_bounds__(256) void prep_weff(
    const float* __restrict__ w3, const float* __restrict__ w5,
    const float* __restrict__ w7, const float* __restrict__ wf,
    float* __restrict__ Weff)
{
    const int c = blockIdx.x;
    __shared__ float lwf[C_OUT * 49];
    __shared__ float lw3[9 * 9];
    __shared__ float lw5[16 * 25];
    __shared__ float lw7[24 * 49];
    const int tid = threadIdx.x;

    for (int idx = tid; idx < C_OUT * 49; idx += 256) {
        int o = idx / 49, k = idx % 49;
        int j = (k < 9)  ? (c * 9 + k)
              : (k < 25) ? (288 + c * 16 + (k - 9))
                         : (800 + c * 24 + (k - 25));
        lwf[idx] = wf[o * 1568 + j];
    }
    for (int idx = tid; idx < 81;   idx += 256) lw3[idx] = w3[c * 81 + idx];
    for (int idx = tid; idx < 400;  idx += 256) lw5[idx] = w5[c * 400 + idx];
    for (int idx = tid; idx < 1176; idx += 256) lw7[idx] = w7[c * 1176 + idx];
    __syncthreads();

    for (int idx = tid; idx < 49 * C_OUT; idx += 256) {
        int o = idx % C_OUT;        // o fastest -> coalesced store
        int p = idx / C_OUT;
        int ky = p / 7, kx = p % 7;
        float acc = 0.f;
        if (ky >= 2 && ky <= 4 && kx >= 2 && kx <= 4) {
            int pos = (ky - 2) * 3 + (kx - 2);
            #pragma unroll
            for (int k = 0; k < 9; ++k)
                acc += lwf[o * 49 + k] * lw3[k * 9 + pos];
        }
        if (ky >= 1 && ky <= 5 && kx >= 1 && kx <= 5) {
            int pos = (ky - 1) * 5 + (kx - 1);
            #pragma unroll
            for (int k = 0; k < 16; ++k)
                acc += lwf[o * 49 + 9 + k] * lw5[k * 25 + pos];
        }
        {
            int pos = ky * 7 + kx;
            #pragma unroll
            for (int k = 0; k < 24; ++k)
                acc += lwf[o * 49 + 25 + k] * lw7[k * 49 + pos];
        }
        Weff[(c * 49 + p) * C_OUT + o] = acc;
    }
}

__global__ __launch_bounds__(256) void prep_beff(
    const float* __restrict__ b3, const float* __restrict__ b5,
    const float* __restrict__ b7, const float* __restrict__ wf,
    const float* __restrict__ bf, float* __restrict__ Beff)
{
    const int o = blockIdx.x;
    const int tid = threadIdx.x;
    float acc = 0.f;
    for (int j = tid; j < 1568; j += 256) {
        float bj = (j < 288) ? b3[j] : (j < 800) ? b5[j - 288] : b7[j - 800];
        acc += wf[o * 1568 + j] * bj;
    }
    __shared__ float red[256];
    red[tid] = acc;
    __syncthreads();
    for (int s = 128; s > 0; s >>= 1) {
        if (tid < s) red[tid] += red[tid + s];
        __syncthreads();
    }
    if (tid == 0) Beff[o] = red[0] + bf[o];
}

// Block: 512 threads = 8 waves. Each wave = one oc-quad team (4 output chans).
// Thread: 4 consecutive pixels (w) x 4 output channels = 16 accumulators.
// Grid z: batch * 2 oc-halves (oc 0-31 / 32-63).
__global__ __launch_bounds__(512, 4) void conv7(
    const float* __restrict__ x, const float* __restrict__ Weff,
    const float* __restrict__ Beff, float* __restrict__ out)
{
    __shared__ float xt[C_IN][HALO][RSTRIDE];   // 32*22*24*4 = 67584 B
    const int b      = blockIdx.z >> 1;
    const int ochalf = blockIdx.z & 1;
    const int h0 = blockIdx.y * TILE;
    const int w0 = blockIdx.x * TILE;
    const int tid = threadIdx.x;

    const float* xb = x + (size_t)b * C_IN * HH * WW;
    for (int idx = tid; idx < C_IN * HALO * RSTRIDE; idx += 512) {
        int c   = idx / (HALO * RSTRIDE);
        int rem = idx - c * (HALO * RSTRIDE);
        int r   = rem / RSTRIDE, col = rem - r * RSTRIDE;
        int h = h0 + r - PAD, w = w0 + col - PAD;
        float v = 0.f;
        if (col < HALO && h >= 0 && h < HH && w >= 0 && w < WW)
            v = xb[(c * HH + h) * WW + w];
        (&xt[0][0][0])[idx] = v;
    }
    __syncthreads();

    const int tx4  = tid & 3;               // pixel group (4 px each)
    const int ty   = (tid >> 2) & 15;       // output row
    const int wave = __builtin_amdgcn_readfirstlane(tid >> 6);  // wave-uniform -> SGPR
    const int oc0  = ochalf * 32 + wave * 4;

    float acc[4][4] = {};                   // [o][px]
    const float* __restrict__ wbase = Weff + oc0;

    for (int c = 0; c < C_IN; ++c) {
        #pragma unroll
        for (int dy = 0; dy < 7; ++dy) {
            const float* xrow = &xt[c][ty + dy][tx4 * 4];
            float xr[10];
            *(float4*)(&xr[0]) = *(const float4*)(&xrow[0]);
            *(float4*)(&xr[4]) = *(const float4*)(&xrow[4]);
            *(float2*)(&xr[8]) = *(const float2*)(&xrow[8]);
            const float* __restrict__ wq = wbase + (c * 49 + dy * 7) * C_OUT;
            #pragma unroll
            for (int dx = 0; dx < 7; ++dx) {
                float wv[4];
                #pragma unroll
                for (int o = 0; o < 4; ++o) wv[o] = wq[dx * C_OUT + o];
                #pragma unroll
                for (int o = 0; o < 4; ++o)
                    #pragma unroll
                    for (int px = 0; px < 4; ++px)
                        acc[o][px] += xr[px + dx] * wv[o];
            }
        }
    }

    const int hh = h0 + ty;
    const int wwb = w0 + tx4 * 4;
    #pragma unroll
    for (int o = 0; o < 4; ++o) {
        float bias = Beff[oc0 + o];
        float4 v;
        v.x = acc[o][0] + bias;
        v.y = acc[o][1] + bias;
        v.z = acc[o][2] + bias;
        v.w = acc[o][3] + bias;
        *(float4*)&out[(((size_t)b * C_OUT + oc0 + o) * HH + hh) * WW + wwb] = v;
    }
}

extern "C" void kernel_launch(void* const* d_in, const int* in_sizes, int n_in,
                              void* d_out, int out_size, void* d_ws, size_t ws_size,
                              hipStream_t stream) {
    const float* x  = (const float*)d_in[0];
    const float* w3 = (const float*)d_in[1];
    const float* b3 = (const float*)d_in[2];
    const float* w5 = (const float*)d_in[3];
    const float* b5 = (const float*)d_in[4];
    const float* w7 = (const float*)d_in[5];
    const float* b7 = (const float*)d_in[6];
    const float* wf = (const float*)d_in[7];
    const float* bf = (const float*)d_in[8];
    float* outp = (float*)d_out;

    float* Weff = (float*)d_ws;
    float* Beff = Weff + C_IN * 49 * C_OUT;

    prep_weff<<<C_IN, 256, 0, stream>>>(w3, w5, w7, wf, Weff);
    prep_beff<<<C_OUT, 256, 0, stream>>>(b3, b5, b7, wf, bf, Beff);

    dim3 grid(WW / TILE, HH / TILE, BATCH * 2);
    conv7<<<grid, 512, 0, stream>>>(x, Weff, Beff, outp);
}